// Round 11
// baseline (411.879 us; speedup 1.0000x reference)
//
#include <hip/hip_runtime.h>

#define T_SZ 65536
#define K_SZ 2048
#define D_SZ 256

typedef unsigned short u16;
typedef _Float16 f16;
typedef f16 f16x8 __attribute__((ext_vector_type(8)));
typedef float f32x4 __attribute__((ext_vector_type(4)));

// Candidate ring capacity (per 64-row block). Post-chunk-min gate load is
// ~winners + near-ties; 1024 is >4x headroom. Overflow -> exact full scan
// fallback (correct, slow, statistically unreachable with the warmed gate).
#define RINGCAP 1024

// bank-swizzle key for 16B k-groups within a 64B row, baked into the E image
// by conv_e and inverted at fragment-read time (G21: both-sides-or-neither).
// For the global-read path it is correctness-neutral and keeps each fragment
// load covering a full contiguous 1KB region (16 lines / 64 lanes).
__device__ __forceinline__ int swz4(int r) { return (r & 3) ^ ((r >> 2) & 3); }

// numpy pairwise_sum replica for 128 contiguous squared elements, float4
// loads (identical FP op sequence to the harness-verified scalar version).
__device__ __forceinline__ float pairwise128_sq_v4(const float4* __restrict__ a4) {
#pragma clang fp contract(off)
  float4 va = a4[0], vb = a4[1];
  float r0 = va.x * va.x, r1 = va.y * va.y, r2 = va.z * va.z, r3 = va.w * va.w;
  float r4 = vb.x * vb.x, r5 = vb.y * vb.y, r6 = vb.z * vb.z, r7 = vb.w * vb.w;
#pragma unroll
  for (int i = 2; i < 32; i += 2) {
    float4 c = a4[i], d = a4[i + 1];
    r0 += c.x * c.x;
    r1 += c.y * c.y;
    r2 += c.z * c.z;
    r3 += c.w * c.w;
    r4 += d.x * d.x;
    r5 += d.y * d.y;
    r6 += d.z * d.z;
    r7 += d.w * d.w;
  }
  return ((r0 + r1) + (r2 + r3)) + ((r4 + r5) + (r6 + r7));
}

// Same exact chain + loose |x| sum (only feeds our own rigorous error bound).
__device__ __forceinline__ float2 pairwise128_sq_abs_v4(const float4* __restrict__ a4) {
#pragma clang fp contract(off)
  float4 va = a4[0], vb = a4[1];
  float r0 = va.x * va.x, r1 = va.y * va.y, r2 = va.z * va.z, r3 = va.w * va.w;
  float r4 = vb.x * vb.x, r5 = vb.y * vb.y, r6 = vb.z * vb.z, r7 = vb.w * vb.w;
  float s0 = fabsf(va.x) + fabsf(va.y), s1 = fabsf(va.z) + fabsf(va.w);
  float s2 = fabsf(vb.x) + fabsf(vb.y), s3 = fabsf(vb.z) + fabsf(vb.w);
#pragma unroll
  for (int i = 2; i < 32; i += 2) {
    float4 c = a4[i], d = a4[i + 1];
    r0 += c.x * c.x;
    r1 += c.y * c.y;
    r2 += c.z * c.z;
    r3 += c.w * c.w;
    r4 += d.x * d.x;
    r5 += d.y * d.y;
    r6 += d.z * d.z;
    r7 += d.w * d.w;
    s0 += fabsf(c.x) + fabsf(c.y);
    s1 += fabsf(c.z) + fabsf(c.w);
    s2 += fabsf(d.x) + fabsf(d.y);
    s3 += fabsf(d.z) + fabsf(d.w);
  }
  float2 res;
  res.x = ((r0 + r1) + (r2 + r3)) + ((r4 + r5) + (r6 + r7));
  res.y = (s0 + s1) + (s2 + s3);
  return res;
}

__global__ void esq_kernel(const float* __restrict__ e, float* __restrict__ esq) {
  int k = blockIdx.x * 64 + threadIdx.x;
  const float4* er = reinterpret_cast<const float4*>(e + (size_t)k * D_SZ);
  esq[k] = pairwise128_sq_v4(er) + pairwise128_sq_v4(er + 32);
}

// E: fp32 rows -> pre-tiled, pre-swizzled fp16 image (RNE via v_cvt_f16_f32).
// Per 128-row tile (32768 u16): [kstep 0..7][row 0..127][G 0..3][j 0..7],
// element (row, k = kstep*32 + 8*(G ^ swz4(row)) + j).
__global__ __launch_bounds__(256) void conv_e_kernel(const float* __restrict__ src,
                                                     u16* __restrict__ dst) {
  const int tile = blockIdx.x, tid = threadIdx.x;
  const float4* s4 = reinterpret_cast<const float4*>(src);
  u16* dt = dst + (size_t)tile * 32768;
#pragma unroll 1
  for (int it = 0; it < 16; ++it) {
    int idx = tid + it * 256;  // 0..4095
    int G = idx & 3, row = (idx >> 2) & 127, step = idx >> 9;  // step 0..7
    int srow = tile * 128 + row;
    int kb = step * 32 + 8 * (G ^ swz4(row));
    float4 a = s4[srow * 64 + (kb >> 2)];
    float4 b = s4[srow * 64 + (kb >> 2) + 1];
    float v[8] = {a.x, a.y, a.z, a.w, b.x, b.y, b.z, b.w};
    union { f16 h[8]; uint4 vec; } pk;
#pragma unroll
    for (int j = 0; j < 8; ++j) pk.h[j] = (f16)v[j];
    *reinterpret_cast<uint4*>(dt + (size_t)step * 4096 + row * 32 + G * 8) = pk.vec;
  }
}

// Exact cross term: sequential fmaf chain over d=0..255 -- bit-identical to the
// harness-verified chain from previous rounds.
__device__ __forceinline__ float exact_cross(const float4* __restrict__ x4,
                                             const float4* __restrict__ e4,
                                             int grow, int code) {
  const float4* xr = x4 + (size_t)grow * 64;
  const float4* er = e4 + (size_t)code * 64;
  float acc = 0.0f;
#pragma unroll 8
  for (int t = 0; t < 64; ++t) {
    float4 a = xr[t], b = er[t];
    acc = __builtin_fmaf(a.x, b.x, acc);
    acc = __builtin_fmaf(a.y, b.y, acc);
    acc = __builtin_fmaf(a.z, b.z, acc);
    acc = __builtin_fmaf(a.w, b.w, acc);
  }
  return acc;
}

// Fused fp16 MFMA GEMM, barrier-free K-loop. R11 structural change: pin the
// register allocator at 3 waves/SIMD (amdgpu_waves_per_eu(3,3), ~170-reg cap)
// -- R9/R10 showed the allocator targeting 8 waves/SIMD (64 VGPR) that LDS
// could never deliver, destroying all load ILP. Budget now spent on:
//   af[2][8]  = 64 regs : ALL A fragments, converted fp32->fp16 in-register
//               straight from global x (same RNE cvt + fragment k-layout as
//               the proven LDS path -- bit-identical operands). Zero ds_read,
//               zero staging, LDS 38.9KB -> 5.6KB.
//   bpf[2][4] = 32 regs : B double-buffer from the L2-resident global image.
//   acc       = 32 regs.  Total demand ~148 <= 168 cap: nothing can spill.
// Two-pass post-chunk-min gated ring, exact rescoring, gather + STE output.
// Block = 256 thr (2x2 waves; wave tile 32 rows x 64 cols), grid 1024.
__global__ __launch_bounds__(256)
__attribute__((amdgpu_waves_per_eu(3, 3))) void vq_mfma_kernel(
    const float* __restrict__ x, const float* __restrict__ e,
    const u16* __restrict__ Eh, const float* __restrict__ esq_g,
    float* __restrict__ out, float* __restrict__ outIdx) {
  __shared__ float xsq_s[64], th_s[64];
  __shared__ unsigned rm1_u[64];  // running min dist (uint-ordered)
  __shared__ unsigned ring[RINGCAP];
  __shared__ unsigned long long ebest[64];
  __shared__ int fidx[64];
  __shared__ unsigned ringcnt;

  const int tid = threadIdx.x;
  const int lane = tid & 63;
  const int wm = (tid >> 6) >> 1, wn = (tid >> 6) & 1;  // 2x2 wave grid
  const int rowbase = blockIdx.x * 64;

  if (tid == 0) ringcnt = 0;
  if (tid < 64) {
    ebest[tid] = ~0ull;
    rm1_u[tid] = 0x7F7FFFFFu;  // +FLT_MAX
  }

  const float4* x4 = reinterpret_cast<const float4*>(x);

  // per-thread constant B offsets (u16 units, within one kstep slice)
  int offB[4];
#pragma unroll
  for (int nf = 0; nf < 4; ++nf) {
    const int cl = wn * 64 + nf * 16 + (lane & 15);
    offB[nf] = cl * 32 + (((lane >> 4) ^ swz4(cl)) * 8);
  }

  // B prefetch prologue: gs=0 into parity buffer 0 (issued before A-conv so
  // the L2 latency hides under the conversion VALU work).
  f16x8 bpf[2][4];
#pragma unroll
  for (int nf = 0; nf < 4; ++nf)
    bpf[0][nf] = *reinterpret_cast<const f16x8*>(Eh + offB[nf]);

  // ---- A fragments: fp32 -> fp16 in-register, straight from x.
  // Fragment element j of (mf, ks): x[rowA][ks*32 + (lane>>4)*8 + j]
  // == 2 contiguous float4 loads; RNE cvt identical to the image path. ----
  f16x8 af[2][8];
#pragma unroll
  for (int mf = 0; mf < 2; ++mf) {
    const int rowA = rowbase + wm * 32 + mf * 16 + (lane & 15);
    const size_t base = (size_t)rowA * 64 + (lane >> 4) * 2;
#pragma unroll
    for (int ks = 0; ks < 8; ++ks) {
      float4 a = x4[base + ks * 8];
      float4 b = x4[base + ks * 8 + 1];
      f16x8 t;
      t[0] = (f16)a.x; t[1] = (f16)a.y; t[2] = (f16)a.z; t[3] = (f16)a.w;
      t[4] = (f16)b.x; t[5] = (f16)b.y; t[6] = (f16)b.z; t[7] = (f16)b.w;
      af[mf][ks] = t;
    }
  }

  if (tid < 64) {
    const float4* xr = x4 + (size_t)(rowbase + tid) * 64;  // L2-hot
    float2 p0 = pairwise128_sq_abs_v4(xr);
    float2 p1 = pairwise128_sq_abs_v4(xr + 32);
    xsq_s[tid] = p0.x + p1.x;
    // Rigorous per-row band threshold (>=2x margin over the derived
    // |approx-exact| dist bound 1.94e-6*Sa + 1.24e-4). Harness-proven in
    // six prior passing rounds -- do not tighten.
    th_s[tid] = 4.0e-6f * (p0.y + p1.y) + 4.0e-4f;
  }

  f32x4 acc[2][4];
#pragma unroll
  for (int mf = 0; mf < 2; ++mf)
#pragma unroll
    for (int nf = 0; nf < 4; ++nf) acc[mf][nf] = (f32x4){0.f, 0.f, 0.f, 0.f};

  __syncthreads();  // xsq_s/th_s/rm1_u visible before first epilogue

#pragma unroll 1
  for (int chunk = 0; chunk < 16; ++chunk) {
    float esq_c[4];
#pragma unroll
    for (int nf = 0; nf < 4; ++nf)
      esq_c[nf] = esq_g[chunk * 128 + wn * 64 + nf * 16 + (lane & 15)];
#pragma unroll
    for (int ks = 0; ks < 8; ++ks) {       // fully unrolled: parity static
      const int par = ks & 1;
      const int gsn = chunk * 8 + ks + 1;  // next kstep (crosses chunks)
      if (gsn < 128) {
        const u16* bg = Eh + (size_t)gsn * 4096;
#pragma unroll
        for (int nf = 0; nf < 4; ++nf)
          bpf[par ^ 1][nf] = *reinterpret_cast<const f16x8*>(bg + offB[nf]);
      }
#pragma unroll
      for (int mf = 0; mf < 2; ++mf)
#pragma unroll
        for (int nf = 0; nf < 4; ++nf)
          acc[mf][nf] = __builtin_amdgcn_mfma_f32_16x16x32_f16(
              af[mf][ks], bpf[par][nf], acc[mf][nf], 0, 0, 0);
    }
    // ---- pass 1: per-row chunk min -> rm1 (shuffle-reduced, 1 atomic/row).
    // Warms the gate BEFORE any recording: chunk 0 cannot flood the ring. ----
#pragma unroll
    for (int mf = 0; mf < 2; ++mf) {
#pragma unroll
      for (int rg = 0; rg < 4; ++rg) {
        const int row = wm * 32 + mf * 16 + (lane >> 4) * 4 + rg;  // C layout (m89)
        const float xq = xsq_s[row];
        float dmin = 3.4e38f;
#pragma unroll
        for (int nf = 0; nf < 4; ++nf)
          dmin = fminf(dmin, (xq - 2.0f * acc[mf][nf][rg]) + esq_c[nf]);
        dmin = fminf(dmin, __shfl_xor(dmin, 1, 64));
        dmin = fminf(dmin, __shfl_xor(dmin, 2, 64));
        dmin = fminf(dmin, __shfl_xor(dmin, 4, 64));
        dmin = fminf(dmin, __shfl_xor(dmin, 8, 64));
        if ((lane & 15) == 0) atomicMin(&rm1_u[row], __float_as_uint(dmin));
      }
    }
    __syncthreads();
    // ---- pass 2: record with post-chunk-min gate. Sound: rm_used >= rm_final
    // always (monotone atomicMin), th >= 2*err -> winner + all possible ties
    // recorded. No trailing barrier: later atomics only LOWER rm1. ----
    const int cbase = chunk * 128 + wn * 64;
#pragma unroll
    for (int mf = 0; mf < 2; ++mf) {
#pragma unroll
      for (int rg = 0; rg < 4; ++rg) {
        const int row = wm * 32 + mf * 16 + (lane >> 4) * 4 + rg;
        const float xq = xsq_s[row];
        const float gate = __uint_as_float(rm1_u[row]) + th_s[row];
#pragma unroll
        for (int nf = 0; nf < 4; ++nf) {
          const float dv = (xq - 2.0f * acc[mf][nf][rg]) + esq_c[nf];
          if (dv <= gate) {
            unsigned slot = atomicAdd(&ringcnt, 1u);
            if (slot < RINGCAP)
              ring[slot] = ((unsigned)row << 11) |
                           (unsigned)(cbase + nf * 16 + (lane & 15));
          }
          acc[mf][nf][rg] = 0.0f;
        }
      }
    }
  }
  __syncthreads();

  // ---- exact rescoring of every ring entry (winner + all ties provably in) --
  const float4* e4 = reinterpret_cast<const float4*>(e);
  const unsigned cnt = ringcnt;
  if (cnt <= RINGCAP) {
    for (unsigned i = tid; i < cnt; i += 256) {
      const unsigned ent = ring[i];
      const int row = (int)(ent >> 11), code = (int)(ent & 2047u);
      const float cr = exact_cross(x4, e4, rowbase + row, code);
      const float d = (xsq_s[row] - 2.0f * cr) + esq_g[code];
      const unsigned long long key =
          (((unsigned long long)__float_as_uint(d)) << 32) | (unsigned)code;
      atomicMin(&ebest[row], key);  // min dist, tie -> lowest code (np rule)
    }
  } else {  // overflow (statistically unreachable): full exact scan
#pragma unroll 1
    for (int row = 0; row < 64; ++row) {
      for (int code = tid; code < K_SZ; code += 256) {
        const float cr = exact_cross(x4, e4, rowbase + row, code);
        const float d = (xsq_s[row] - 2.0f * cr) + esq_g[code];
        const unsigned long long key =
            (((unsigned long long)__float_as_uint(d)) << 32) | (unsigned)code;
        atomicMin(&ebest[row], key);
      }
    }
  }
  __syncthreads();
  if (tid < 64) fidx[tid] = (int)(ebest[tid] & 2047ull);
  __syncthreads();

  // ---- output: gather + STE, fully coalesced ----
  float4* out4 = reinterpret_cast<float4*>(out);
#pragma unroll 1
  for (int i = tid; i < 64 * 64; i += 256) {
    const int row = i >> 6, q = i & 63;
    const int idx = fidx[row];
    float4 xv = x4[(size_t)(rowbase + row) * 64 + q];
    float4 qv = e4[(size_t)idx * 64 + q];
    float4 o;
    o.x = xv.x + (qv.x - xv.x);
    o.y = xv.y + (qv.y - xv.y);
    o.z = xv.z + (qv.z - xv.z);
    o.w = xv.w + (qv.w - xv.w);
    out4[(size_t)(rowbase + row) * 64 + q] = o;
    if (q == 0) outIdx[rowbase + row] = (float)idx;
  }
}

extern "C" void kernel_launch(void* const* d_in, const int* in_sizes, int n_in,
                              void* d_out, int out_size, void* d_ws, size_t ws_size,
                              hipStream_t stream) {
  const float* x = (const float*)d_in[0];  // (65536, 256) fp32
  const float* e = (const float*)d_in[1];  // (2048, 256) fp32
  float* out = (float*)d_out;              // [T*D quantized | T indices-as-float]
  float* outIdx = out + (size_t)T_SZ * D_SZ;

  float* esq = (float*)d_ws;     // 2048 floats
  u16* Eh = (u16*)(esq + K_SZ);  // 1 MB fp16 codebook image

  conv_e_kernel<<<K_SZ / 128, 256, 0, stream>>>(e, Eh);
  esq_kernel<<<K_SZ / 64, 64, 0, stream>>>(e, esq);
  vq_mfma_kernel<<<T_SZ / 64, 256, 0, stream>>>(x, e, Eh, esq, out, outIdx);
}